// Round 4
// baseline (417.509 us; speedup 1.0000x reference)
//
#include <hip/hip_runtime.h>
#include <math.h>

#define SEQ 30
#define H 64
#define VOCAB 128000

#define NB 1000
#define ITERS 8               // rows per block = 16 * ITERS = 128
#define ROWS_PER_BLOCK 128

// ws float offsets
#define WS_M     0            // [0, NB)      per-block LSE max
#define WS_S     1024         // [1024, +NB)  per-block LSE sum
#define WS_H     2048         // [2048, +64)  h_new
#define WS_LSE   2112         // scalar lse
#define WS_FLAGS 4096         // 3 u32: flag_h, flag_lse, counter (memset 0 per call)

__global__ void __launch_bounds__(256, 4) fused_kernel(
        const float* __restrict__ input,
        const float* __restrict__ hidden,
        const float* __restrict__ W_ih,
        const float* __restrict__ W_hh,
        const float* __restrict__ b_ih,
        const float* __restrict__ b_hh,
        const float* __restrict__ W_out,
        const float* __restrict__ b_out,
        float* __restrict__ out,
        float* __restrict__ ws,
        unsigned* __restrict__ flags) {
    __shared__ float xs[H], h0s[H], gx[3 * H], gh[3 * H];
    __shared__ float slog[ROWS_PER_BLOCK], pm[16], ps[16];
    __shared__ float rm[256], rs[256];
    __shared__ int sLast;

    const int t = threadIdx.x;
    const int sub = t & 15;
    const int grp = t >> 4;
    const int bid = blockIdx.x;
    const int base = bid * ROWS_PER_BLOCK;
    const float4* __restrict__ W4 = (const float4*)W_out;

    float4 w[ITERS];
    float bo[ITERS];

    if (bid != 0) {
        // 1) issue the HBM stream immediately (flat idx = base*16 + it*256 + t)
#pragma unroll
        for (int it = 0; it < ITERS; ++it) {
            w[it]  = W4[(base + it * 16 + grp) * 16 + sub];
            bo[it] = b_out[base + it * 16 + grp];
        }
        __builtin_amdgcn_sched_barrier(0);  // don't let loads sink below the spin
        // 2) wait for h_new; spin does NOT drain vmcnt -> stream keeps flowing
        while (__hip_atomic_load(&flags[0], __ATOMIC_ACQUIRE,
                                 __HIP_MEMORY_SCOPE_AGENT) == 0u)
            __builtin_amdgcn_s_sleep(2);
    } else {
        // ---- block 0: GRU with no pending prefetch (fast barriers) ----
        if (t < H) {
            float s = 0.f;  // softmax over singleton axis => weights all 1.0
#pragma unroll
            for (int i = 0; i < SEQ; ++i) s += input[i * H + t];
            xs[t] = s;
            h0s[t] = hidden[t];
        }
        __syncthreads();
        if (t < 3 * H) {
            float a = b_ih[t], b = b_hh[t];
            const float4* wi = (const float4*)(W_ih + t * H);
            const float4* wh = (const float4*)(W_hh + t * H);
            const float4* x4 = (const float4*)xs;
            const float4* h4 = (const float4*)h0s;
#pragma unroll
            for (int j = 0; j < H / 4; ++j) {
                const float4 wiv = wi[j], whv = wh[j], xv = x4[j], hv2 = h4[j];
                a += wiv.x * xv.x + wiv.y * xv.y + wiv.z * xv.z + wiv.w * xv.w;
                b += whv.x * hv2.x + whv.y * hv2.y + whv.z * hv2.z + whv.w * hv2.w;
            }
            gx[t] = a;
            gh[t] = b;
        }
        __syncthreads();
        if (t < H) {
            const float r = 1.f / (1.f + expf(-(gx[t] + gh[t])));
            const float z = 1.f / (1.f + expf(-(gx[H + t] + gh[H + t])));
            const float n = tanhf(gx[2 * H + t] + r * gh[2 * H + t]);
            const float hn = (1.f - z) * n + z * h0s[t];
            out[VOCAB + t] = hn;  // second tuple output
            __hip_atomic_store(&ws[WS_H + t], hn, __ATOMIC_RELAXED,
                               __HIP_MEMORY_SCOPE_AGENT);
        }
        __threadfence();
        __syncthreads();
        if (t == 0)
            __hip_atomic_store(&flags[0], 1u, __ATOMIC_RELEASE,
                               __HIP_MEMORY_SCOPE_AGENT);
        // block 0's own chunk, issued late (stream mostly queued by now)
#pragma unroll
        for (int it = 0; it < ITERS; ++it) {
            w[it]  = W4[(base + it * 16 + grp) * 16 + sub];
            bo[it] = b_out[base + it * 16 + grp];
        }
    }

    // ---- h fragment (agent-scope loads: bypass stale caches across XCDs) ----
    float h0v = __hip_atomic_load(&ws[WS_H + sub * 4 + 0], __ATOMIC_RELAXED, __HIP_MEMORY_SCOPE_AGENT);
    float h1v = __hip_atomic_load(&ws[WS_H + sub * 4 + 1], __ATOMIC_RELAXED, __HIP_MEMORY_SCOPE_AGENT);
    float h2v = __hip_atomic_load(&ws[WS_H + sub * 4 + 2], __ATOMIC_RELAXED, __HIP_MEMORY_SCOPE_AGENT);
    float h3v = __hip_atomic_load(&ws[WS_H + sub * 4 + 3], __ATOMIC_RELAXED, __HIP_MEMORY_SCOPE_AGENT);

    // ---- dots + per-block LSE partial ----
    float logit[ITERS];
#pragma unroll
    for (int it = 0; it < ITERS; ++it) {
        float d = w[it].x * h0v + w[it].y * h1v + w[it].z * h2v + w[it].w * h3v;
#pragma unroll
        for (int off = 1; off < 16; off <<= 1) d += __shfl_xor(d, off);
        logit[it] = d + bo[it];
    }
    if (sub == 0) {
        float m = logit[0];
#pragma unroll
        for (int it = 1; it < ITERS; ++it) m = fmaxf(m, logit[it]);
        float s = 0.f;
#pragma unroll
        for (int it = 0; it < ITERS; ++it) s += expf(logit[it] - m);
        pm[grp] = m;
        ps[grp] = s;
    }
    __syncthreads();
    if (t == 0) {
        float M = pm[0], S = 0.f;
#pragma unroll
        for (int i = 1; i < 16; ++i) M = fmaxf(M, pm[i]);
#pragma unroll
        for (int i = 0; i < 16; ++i) S += ps[i] * expf(pm[i] - M);
        __hip_atomic_store(&ws[WS_M + bid], M, __ATOMIC_RELAXED, __HIP_MEMORY_SCOPE_AGENT);
        __hip_atomic_store(&ws[WS_S + bid], S, __ATOMIC_RELAXED, __HIP_MEMORY_SCOPE_AGENT);
        const unsigned old = __hip_atomic_fetch_add(&flags[2], 1u, __ATOMIC_ACQ_REL,
                                                    __HIP_MEMORY_SCOPE_AGENT);
        sLast = (old == NB - 1);
    }
    __syncthreads();

    // ---- last block: global LSE merge, publish lse ----
    if (sLast) {
        float m = -INFINITY, s = 0.f;
        for (int i = t; i < NB; i += 256) {
            const float m2 = __hip_atomic_load(&ws[WS_M + i], __ATOMIC_RELAXED, __HIP_MEMORY_SCOPE_AGENT);
            const float s2 = __hip_atomic_load(&ws[WS_S + i], __ATOMIC_RELAXED, __HIP_MEMORY_SCOPE_AGENT);
            const float Mn = fmaxf(m, m2);
            s = s * expf(m - Mn) + s2 * expf(m2 - Mn);
            m = Mn;
        }
        rm[t] = m; rs[t] = s;
        __syncthreads();
        for (int off = 128; off > 0; off >>= 1) {
            if (t < off) {
                const float m2 = rm[t + off], s2 = rs[t + off];
                const float Mn = fmaxf(rm[t], m2);
                rs[t] = rs[t] * expf(rm[t] - Mn) + s2 * expf(m2 - Mn);
                rm[t] = Mn;
            }
            __syncthreads();
        }
        if (t == 0) {
            const float lse = rm[0] + logf(rs[0]);
            __hip_atomic_store(&ws[WS_LSE], lse, __ATOMIC_RELAXED, __HIP_MEMORY_SCOPE_AGENT);
            __threadfence();
            __hip_atomic_store(&flags[1], 1u, __ATOMIC_RELEASE, __HIP_MEMORY_SCOPE_AGENT);
        }
    }

    // ---- everyone: wait for lse, subtract, coalesced store ----
    while (__hip_atomic_load(&flags[1], __ATOMIC_ACQUIRE,
                             __HIP_MEMORY_SCOPE_AGENT) == 0u)
        __builtin_amdgcn_s_sleep(2);
    const float lse = __hip_atomic_load(&ws[WS_LSE], __ATOMIC_RELAXED,
                                        __HIP_MEMORY_SCOPE_AGENT);
    if (sub == 0) {
#pragma unroll
        for (int it = 0; it < ITERS; ++it) slog[it * 16 + grp] = logit[it];
    }
    __syncthreads();
    if (t < ROWS_PER_BLOCK) out[base + t] = slog[t] - lse;
}

extern "C" void kernel_launch(void* const* d_in, const int* in_sizes, int n_in,
                              void* d_out, int out_size, void* d_ws, size_t ws_size,
                              hipStream_t stream) {
    const float* input  = (const float*)d_in[0];
    const float* hidden = (const float*)d_in[1];
    // d_in[2] = W_attn, d_in[3] = b_attn: dead (softmax over singleton axis)
    const float* W_ih   = (const float*)d_in[4];
    const float* W_hh   = (const float*)d_in[5];
    const float* b_ih   = (const float*)d_in[6];
    const float* b_hh   = (const float*)d_in[7];
    const float* W_out  = (const float*)d_in[8];
    const float* b_out  = (const float*)d_in[9];
    // d_in[10] = time_step: unused
    float* out = (float*)d_out;
    float* ws  = (float*)d_ws;
    unsigned* flags = (unsigned*)((char*)d_ws + WS_FLAGS * sizeof(float));

    // zero flag_h / flag_lse / counter -> deterministic across replays
    hipMemsetAsync(flags, 0, 3 * sizeof(unsigned), stream);
    fused_kernel<<<NB, 256, 0, stream>>>(input, hidden, W_ih, W_hh, b_ih, b_hh,
                                         W_out, b_out, out, ws, flags);
}

// Round 5
// 22.300 us; speedup vs baseline: 18.7225x; 18.7225x over previous
//
#include <hip/hip_runtime.h>
#include <math.h>

#define SEQ 30
#define H 64
#define VOCAB 128000

// GEMV geometry: 16 lanes per row, 256 threads/block -> 16 rows/iter.
#define NB 1000
#define ITERS 8               // rows per block = 16 * ITERS = 128; 1000*128 = 128000
#define ROWS_PER_BLOCK (16 * ITERS)

// ws layout (floats): [0..NB) per-block max, [1024..1024+NB) sum, [2048..2112) h_new
#define WS_M 0
#define WS_S 1024
#define WS_H 2048

// ---------------- K1: attention-sum + GRU step (1 block) ----------------
__global__ void gru_kernel(const float* __restrict__ input,
                           const float* __restrict__ hidden,
                           const float* __restrict__ W_ih,
                           const float* __restrict__ W_hh,
                           const float* __restrict__ b_ih,
                           const float* __restrict__ b_hh,
                           float* __restrict__ out,
                           float* __restrict__ ws) {
    __shared__ float xs[H], h0s[H], gx[3 * H], gh[3 * H];
    const int t = threadIdx.x;  // 192 threads
    if (t < H) {
        // softmax over singleton axis => attention weights are all 1.0
        float s = 0.f;
#pragma unroll
        for (int i = 0; i < SEQ; ++i) s += input[i * H + t];
        xs[t] = s;
        h0s[t] = hidden[t];
    }
    __syncthreads();
    {
        float a = b_ih[t], b = b_hh[t];
        const float4* wi = (const float4*)(W_ih + t * H);
        const float4* wh = (const float4*)(W_hh + t * H);
        const float4* x4 = (const float4*)xs;
        const float4* h4 = (const float4*)h0s;
#pragma unroll
        for (int j = 0; j < H / 4; ++j) {
            const float4 wiv = wi[j], whv = wh[j], xv = x4[j], hv = h4[j];
            a += wiv.x * xv.x + wiv.y * xv.y + wiv.z * xv.z + wiv.w * xv.w;
            b += whv.x * hv.x + whv.y * hv.y + whv.z * hv.z + whv.w * hv.w;
        }
        gx[t] = a;
        gh[t] = b;
    }
    __syncthreads();
    if (t < H) {
        const float r = 1.f / (1.f + expf(-(gx[t] + gh[t])));
        const float z = 1.f / (1.f + expf(-(gx[H + t] + gh[H + t])));
        const float n = tanhf(gx[2 * H + t] + r * gh[2 * H + t]);
        const float hn = (1.f - z) * n + z * h0s[t];
        ws[WS_H + t] = hn;
        out[VOCAB + t] = hn;   // second tuple output: h_new
    }
}

// ---- K2: logits = h_new @ W_out^T + b_out, coalesced store, LSE partials ----
__global__ void __launch_bounds__(256, 4) logits_kernel(
        const float* __restrict__ W_out,
        const float* __restrict__ b_out,
        float* __restrict__ out,
        float* __restrict__ ws) {
    __shared__ float hs[H];
    __shared__ float slog[ROWS_PER_BLOCK];
    __shared__ float pm[16], ps[16];
    const int t = threadIdx.x;
    const int sub = t & 15;
    const int grp = t >> 4;
    const int base = blockIdx.x * ROWS_PER_BLOCK;
    const float4* __restrict__ W4 = (const float4*)W_out;

    if (t < H) hs[t] = ws[WS_H + t];
    __syncthreads();
    const float4 hv = ((const float4*)hs)[sub];

    float logit[ITERS];
#pragma unroll
    for (int it = 0; it < ITERS; ++it) {
        const int row = base + it * 16 + grp;
        // flat float4 index = base*16 + it*256 + t -> fully sequential per block
        const float4 w = W4[row * 16 + sub];
        float d = w.x * hv.x + w.y * hv.y + w.z * hv.z + w.w * hv.w;
#pragma unroll
        for (int off = 1; off < 16; off <<= 1) d += __shfl_xor(d, off);
        logit[it] = d + b_out[row];
        if (sub == 0) slog[it * 16 + grp] = logit[it];
    }
    if (sub == 0) {
        float m = logit[0];
#pragma unroll
        for (int it = 1; it < ITERS; ++it) m = fmaxf(m, logit[it]);
        float s = 0.f;
#pragma unroll
        for (int it = 0; it < ITERS; ++it) s += expf(logit[it] - m);
        pm[grp] = m;
        ps[grp] = s;
    }
    __syncthreads();
    // coalesced logit store: 128 contiguous floats
    if (t < ROWS_PER_BLOCK) out[base + t] = slog[t];
    if (t == 0) {
        float M = pm[0], S = 0.f;
#pragma unroll
        for (int i = 1; i < 16; ++i) M = fmaxf(M, pm[i]);
#pragma unroll
        for (int i = 0; i < 16; ++i) S += ps[i] * expf(pm[i] - M);
        ws[WS_M + blockIdx.x] = M;
        ws[WS_S + blockIdx.x] = S;
    }
}

// ---- K3: redundant LSE merge (8 KB from L2 per block) + in-place subtract ----
__global__ void __launch_bounds__(256) finish_kernel(float* __restrict__ out,
                                                     const float* __restrict__ ws) {
    __shared__ float pm[256], ps[256];
    const int t = threadIdx.x;
    float m = -INFINITY, s = 0.f;
    for (int i = t; i < NB; i += 256) {
        const float m2 = ws[WS_M + i], s2 = ws[WS_S + i];
        const float Mn = fmaxf(m, m2);
        s = s * expf(m - Mn) + s2 * expf(m2 - Mn);
        m = Mn;
    }
    pm[t] = m; ps[t] = s;
    __syncthreads();
    for (int off = 128; off > 0; off >>= 1) {
        if (t < off) {
            const float m2 = pm[t + off], s2 = ps[t + off];
            const float Mn = fmaxf(pm[t], m2);
            ps[t] = ps[t] * expf(pm[t] - Mn) + s2 * expf(m2 - Mn);
            pm[t] = Mn;
        }
        __syncthreads();
    }
    const float lse = pm[0] + logf(ps[0]);

    // exactly one float4 per thread: 125 blocks * 256 threads = 32000 float4
    const int i = blockIdx.x * 256 + t;
    float4* o4 = (float4*)out;
    float4 v = o4[i];
    v.x -= lse; v.y -= lse; v.z -= lse; v.w -= lse;
    o4[i] = v;
}

extern "C" void kernel_launch(void* const* d_in, const int* in_sizes, int n_in,
                              void* d_out, int out_size, void* d_ws, size_t ws_size,
                              hipStream_t stream) {
    const float* input  = (const float*)d_in[0];
    const float* hidden = (const float*)d_in[1];
    // d_in[2] = W_attn, d_in[3] = b_attn: dead (softmax over singleton axis)
    const float* W_ih   = (const float*)d_in[4];
    const float* W_hh   = (const float*)d_in[5];
    const float* b_ih   = (const float*)d_in[6];
    const float* b_hh   = (const float*)d_in[7];
    const float* W_out  = (const float*)d_in[8];
    const float* b_out  = (const float*)d_in[9];
    // d_in[10] = time_step: unused
    float* out = (float*)d_out;
    float* ws  = (float*)d_ws;

    gru_kernel<<<1, 3 * H, 0, stream>>>(input, hidden, W_ih, W_hh, b_ih, b_hh, out, ws);
    logits_kernel<<<NB, 256, 0, stream>>>(W_out, b_out, out, ws);
    finish_kernel<<<VOCAB / 4 / 256, 256, 0, stream>>>(out, ws);
}